// Round 4
// baseline (57.804 us; speedup 1.0000x reference)
//
#include <hip/hip_runtime.h>
#include <stdint.h>

#define G_NUM 4096
#define BLOCK 256
#define VPT   12
#define CAP   (BLOCK * VPT - 3)   // 3069; mean seg len 2048, sd ~45 -> 22 sigma
#define CLS   256                 // boundary-class capacity

typedef unsigned long long ull;

__device__ __forceinline__ unsigned int order_bits(float f) {
    unsigned int b = __float_as_uint(f);
    return (b & 0x80000000u) ? ~b : (b | 0x80000000u);
}
__device__ __forceinline__ float inv_order_bits(unsigned int ob) {
    return __uint_as_float((ob & 0x80000000u) ? (ob & 0x7FFFFFFFu) : ~ob);
}

// seg_starts (int4-vectorized) + mask dtype detect fused in block 0.
// flag: 0 = int32 mask, 1 = float mask, 2 = byte (bool) mask
__global__ void prep_kernel(const int* __restrict__ batch, int* __restrict__ start,
                            const unsigned int* __restrict__ mraw, int* __restrict__ flag,
                            int E) {
    if (blockIdx.x == 0 && threadIdx.x < 64) {
        int lane = threadIdx.x;
        bool allI = true, allF = true;
        for (int i = lane; i < 256; i += 64) {
            unsigned int w = mraw[i];
            if (w > 1u) allI = false;
            if (w != 0u && w != 0x3F800000u) allF = false;
        }
        allI = __all(allI);
        allF = __all(allF);
        if (lane == 0) *flag = allI ? 0 : (allF ? 1 : 2);
    }
    const int n4 = E >> 2;
    int i4 = blockIdx.x * blockDim.x + threadIdx.x;
    if (i4 >= n4) return;
    int4 b = ((const int4*)batch)[i4];
    int prev = __shfl_up(b.w, 1, 64);
    if ((threadIdx.x & 63) == 0) prev = (i4 == 0) ? -1 : batch[i4 * 4 - 1];
    const int e0 = i4 * 4;
    for (int g = prev + 1; g <= b.x; ++g) start[g] = e0;
    for (int g = b.x + 1; g <= b.y; ++g) start[g] = e0 + 1;
    for (int g = b.y + 1; g <= b.z; ++g) start[g] = e0 + 2;
    for (int g = b.z + 1; g <= b.w; ++g) start[g] = e0 + 3;
    if (i4 == n4 - 1) {
        int last = b.w, e = E & ~3;
        for (int t = 0; t < (E & 3); ++t) {
            int v = batch[e + t];
            for (int g = last + 1; g <= v; ++g) start[g] = e + t;
            last = v;
        }
        for (int g = last + 1; g <= G_NUM; ++g) start[g] = E;
    }
}

// 256-bucket suffix scan + k-th bucket select. Self-clears hist, resets *cnt2.
__device__ __forceinline__ void scan_select(
    unsigned int* hist, unsigned int* wtot, int kk,
    int* bsel_s, unsigned int* cgt_s, unsigned int* hsel_s, int* cnt2, int tid)
{
    unsigned int h = hist[tid];
    hist[tid] = 0u;                      // own slot only: pre-clears next round
    unsigned int v = h;
    int lane = tid & 63, wv = tid >> 6;
    #pragma unroll
    for (int off = 1; off < 64; off <<= 1) {
        unsigned int o = __shfl_down(v, off, 64);
        if (lane + off < 64) v += o;
    }
    if (lane == 0) wtot[wv] = v;
    if (tid == 0) *cnt2 = 0;
    __syncthreads();
    unsigned int sfx = v;
    for (int w = wv + 1; w < 4; ++w) sfx += wtot[w];
    if ((unsigned)kk <= sfx && (unsigned)kk > sfx - h) {
        *bsel_s = tid; *cgt_s = sfx - h; *hsel_s = h;
    }
    __syncthreads();
}

__global__ __launch_bounds__(BLOCK) void topk_kernel(
    const float* __restrict__ scores, const void* __restrict__ maskp,
    const int* __restrict__ start, const int* __restrict__ kp,
    const int* __restrict__ flagp, float* __restrict__ out_mask,
    float* __restrict__ out_scores, int E)
{
    __shared__ unsigned int hist[256];
    __shared__ unsigned int wtot[4];
    __shared__ ull cls[CLS];
    __shared__ int cnt, cnt2, bsel_s, licut_s;
    __shared__ unsigned int cgt_s, hsel_s, P_s;

    const int g  = blockIdx.x;
    const int s0 = start[g];
    const int s1 = start[g + 1];
    const int len = s1 - s0;
    if (len <= 0) return;

    const int k     = *kp;
    const int mflag = *flagp;
    const int tid   = threadIdx.x;

    auto getmask = [&](int i) -> bool {
        if (mflag == 2) return ((const unsigned char*)maskp)[i] != 0;
        if (mflag == 0) return ((const int*)maskp)[i] != 0;
        return ((const float*)maskp)[i] != 0.0f;
    };

    if (k <= 0) {
        for (int i = s0 + tid; i < s1; i += BLOCK) { out_mask[i] = 0.0f; out_scores[i] = 0.0f; }
        return;
    }

    hist[tid] = 0u;
    if (tid == 0) cnt = 0;

    if (len <= CAP) {
        const int a0   = s0 & ~3;          // 16B-aligned base
        const int base = a0 + tid * VPT;
        unsigned int key[VPT];
        unsigned int candm = 0u, validm = 0u;
        const bool interior = (base >= s0) && (base + VPT <= s1);

        if (interior) {
            validm = 0xFFFu;
            const float4* sp = (const float4*)(scores + base);
            #pragma unroll
            for (int q = 0; q < 3; ++q) {
                float4 f = sp[q];
                key[4*q]   = order_bits(f.x);
                key[4*q+1] = order_bits(f.y);
                key[4*q+2] = order_bits(f.z);
                key[4*q+3] = order_bits(f.w);
            }
            if (mflag == 2) {
                const unsigned int* mp = (const unsigned int*)((const unsigned char*)maskp + base);
                #pragma unroll
                for (int q = 0; q < 3; ++q) {
                    unsigned int w = mp[q];
                    #pragma unroll
                    for (int j = 0; j < 4; ++j)
                        if ((w >> (8*j)) & 0xFFu) candm |= 1u << (4*q + j);
                }
            } else if (mflag == 0) {
                const int4* mp = (const int4*)((const int*)maskp + base);
                #pragma unroll
                for (int q = 0; q < 3; ++q) {
                    int4 w = mp[q];
                    if (w.x) candm |= 1u << (4*q);
                    if (w.y) candm |= 1u << (4*q + 1);
                    if (w.z) candm |= 1u << (4*q + 2);
                    if (w.w) candm |= 1u << (4*q + 3);
                }
            } else {
                const float4* mp = (const float4*)((const float*)maskp + base);
                #pragma unroll
                for (int q = 0; q < 3; ++q) {
                    float4 w = mp[q];
                    if (w.x != 0.0f) candm |= 1u << (4*q);
                    if (w.y != 0.0f) candm |= 1u << (4*q + 1);
                    if (w.z != 0.0f) candm |= 1u << (4*q + 2);
                    if (w.w != 0.0f) candm |= 1u << (4*q + 3);
                }
            }
        } else if (base < s1) {            // edge thread (front/tail overlap)
            #pragma unroll
            for (int v = 0; v < VPT; ++v) {
                int gi = base + v;
                key[v] = 0u;
                if (gi >= s0 && gi < s1) {
                    validm |= 1u << v;
                    key[v] = order_bits(scores[gi]);
                    if (getmask(gi)) candm |= 1u << v;
                }
            }
        } else {
            #pragma unroll
            for (int v = 0; v < VPT; ++v) key[v] = 0u;
        }

        __syncthreads();                   // B1: hist/cnt clear visible
        int lc = __popc(candm);
        #pragma unroll
        for (int v = 0; v < VPT; ++v)
            if ((candm >> v) & 1u) atomicAdd(&hist[key[v] >> 24], 1u);
        #pragma unroll
        for (int off = 1; off < 64; off <<= 1) lc += __shfl_xor(lc, off, 64);
        if ((tid & 63) == 0) atomicAdd(&cnt, lc);
        __syncthreads();                   // B2: hist + m ready
        const int m = cnt;
        const bool keep_all = (m <= k);
        unsigned int P = 0u;
        int licut = 0;

        if (!keep_all) {
            unsigned int prefix = 0u;
            int kk = k;
            int csel = 0;
            int shift = 24;
            bool have_cls = false;
            for (;;) {
                scan_select(hist, wtot, kk, &bsel_s, &cgt_s, &hsel_s, &cnt2, tid);
                prefix |= ((unsigned int)bsel_s) << shift;
                kk  -= (int)cgt_s;
                csel = (int)hsel_s;
                if (csel <= CLS) { have_cls = true; break; }
                if (shift == 0) break;
                shift -= 8;
                #pragma unroll
                for (int v = 0; v < VPT; ++v)
                    if (((candm >> v) & 1u) && (key[v] >> (shift + 8)) == (prefix >> (shift + 8)))
                        atomicAdd(&hist[(key[v] >> shift) & 0xFFu], 1u);
                __syncthreads();           // hist ready for next round
            }

            if (have_cls) {
                // collect boundary class (shares resolved prefix down to `shift`)
                #pragma unroll
                for (int v = 0; v < VPT; ++v) {
                    if (((candm >> v) & 1u) && (key[v] >> shift) == (prefix >> shift)) {
                        int idx = atomicAdd(&cnt2, 1);
                        cls[idx] = ((ull)key[v] << 32) | (unsigned int)(base + v - s0);
                    }
                }
                __syncthreads();           // cls ready
                if (tid < csel) {
                    ull me = cls[tid];
                    unsigned int km = (unsigned int)(me >> 32), lm = (unsigned int)me;
                    int r = 0;
                    for (int j = 0; j < csel; ++j) {
                        ull o = cls[j];
                        unsigned int ko = (unsigned int)(o >> 32), lo = (unsigned int)o;
                        r += (ko > km || (ko == km && lo < lm)) ? 1 : 0;
                    }
                    if (r == kk - 1) { P_s = km; licut_s = (int)lm; }
                }
                __syncthreads();
                P = P_s; licut = licut_s;
            } else {
                // >CLS identical 32-bit keys: rank by li via ballot-count binary search
                P = prefix;
                int lo = 0, hi = len - 1;
                while (lo < hi) {
                    int mid = (lo + hi) >> 1;
                    if (tid == 0) cnt2 = 0;
                    __syncthreads();
                    int c = 0;
                    #pragma unroll
                    for (int v = 0; v < VPT; ++v)
                        if (((candm >> v) & 1u) && key[v] == prefix && (base + v - s0) <= mid) c++;
                    #pragma unroll
                    for (int off = 1; off < 64; off <<= 1) c += __shfl_xor(c, off, 64);
                    if ((tid & 63) == 0) atomicAdd(&cnt2, c);
                    __syncthreads();
                    int total = cnt2;
                    __syncthreads();
                    if (total >= kk) hi = mid; else lo = mid + 1;
                }
                licut = lo;
            }
        }

        // ---- output straight from registers ----
        if (interior) {
            #pragma unroll
            for (int q = 0; q < 3; ++q) {
                float4 vm, vs;
                float* pm = (float*)&vm;
                float* ps = (float*)&vs;
                #pragma unroll
                for (int j = 0; j < 4; ++j) {
                    int v = 4*q + j;
                    int li = base + v - s0;
                    bool kept = ((candm >> v) & 1u) &&
                        (keep_all || key[v] > P || (key[v] == P && li <= licut));
                    pm[j] = kept ? 1.0f : 0.0f;
                    ps[j] = kept ? inv_order_bits(key[v]) : 0.0f;
                }
                *(float4*)(out_mask   + base + 4*q) = vm;
                *(float4*)(out_scores + base + 4*q) = vs;
            }
        } else if (base < s1) {
            #pragma unroll
            for (int v = 0; v < VPT; ++v) {
                int gi = base + v;
                if (gi < s0 || gi >= s1) continue;
                int li = gi - s0;
                bool kept = ((candm >> v) & 1u) &&
                    (keep_all || key[v] > P || (key[v] == P && li <= licut));
                out_mask[gi]   = kept ? 1.0f : 0.0f;
                out_scores[gi] = kept ? inv_order_bits(key[v]) : 0.0f;
            }
        }
    } else {
        // ---- fallback: global-rescan 64-bit radix (len > CAP; ~never) ----
        __syncthreads();
        int lc = 0;
        for (int i = s0 + tid; i < s1; i += BLOCK)
            if (getmask(i)) lc++;
        atomicAdd(&cnt, lc);
        __syncthreads();
        const int m = cnt;
        const bool keep_all = (m <= k);
        ull pivot = 0ull;
        if (!keep_all) {
            ull prefix = 0ull;
            int kk = k;
            for (int shift = 56; shift >= 0; shift -= 8) {
                for (int i = s0 + tid; i < s1; i += BLOCK) {
                    if (!getmask(i)) continue;
                    ull key = ((ull)order_bits(scores[i]) << 32) |
                              (ull)(0xFFFFFFFFu - (unsigned)(i - s0));
                    if (shift == 56 || (key >> (shift + 8)) == (prefix >> (shift + 8)))
                        atomicAdd(&hist[(unsigned)((key >> shift) & 0xFFull)], 1u);
                }
                __syncthreads();
                scan_select(hist, wtot, kk, &bsel_s, &cgt_s, &hsel_s, &cnt2, tid);
                prefix |= ((ull)(unsigned)bsel_s) << shift;
                kk -= (int)cgt_s;
            }
            pivot = prefix;
        }
        for (int i = s0 + tid; i < s1; i += BLOCK) {
            bool c = getmask(i);
            float sc = 0.0f;
            bool kept = false;
            if (c) {
                sc = scores[i];
                ull key = ((ull)order_bits(sc) << 32) |
                          (ull)(0xFFFFFFFFu - (unsigned)(i - s0));
                kept = keep_all || (key >= pivot);
            }
            out_mask[i]   = kept ? 1.0f : 0.0f;
            out_scores[i] = kept ? sc : 0.0f;
        }
    }
}

extern "C" void kernel_launch(void* const* d_in, const int* in_sizes, int n_in,
                              void* d_out, int out_size, void* d_ws, size_t ws_size,
                              hipStream_t stream) {
    const float* scores = (const float*)d_in[0];
    const int*   batch  = (const int*)d_in[1];
    const void*  mask   = d_in[2];
    const int*   kp     = (const int*)d_in[4];
    const int    E      = in_sizes[0];

    float* out_mask   = (float*)d_out;
    float* out_scores = out_mask + E;

    int* flag  = (int*)d_ws;
    int* start = (int*)((char*)d_ws + 256);

    const int n4 = E >> 2;
    prep_kernel<<<(n4 + BLOCK - 1) / BLOCK, BLOCK, 0, stream>>>(
        batch, start, (const unsigned int*)mask, flag, E);
    topk_kernel<<<G_NUM, BLOCK, 0, stream>>>(scores, mask, start, kp, flag,
                                             out_mask, out_scores, E);
}

// Round 5
// 46.183 us; speedup vs baseline: 1.2516x; 1.2516x over previous
//
#include <hip/hip_runtime.h>
#include <stdint.h>

#define G_NUM 4096
#define BLOCK 256
#define VPT   12
#define CAP   (BLOCK * VPT - 3)   // 3069; mean seg len 2048, sd ~45 -> 22 sigma
#define CLS   256                 // boundary-class capacity
#define HB    2048                // round-1 radix buckets (11 bits)

typedef unsigned long long ull;

__device__ __forceinline__ unsigned int order_bits(float f) {
    unsigned int b = __float_as_uint(f);
    return (b & 0x80000000u) ? ~b : (b | 0x80000000u);
}
__device__ __forceinline__ float inv_order_bits(unsigned int ob) {
    return __uint_as_float((ob & 0x80000000u) ? (ob & 0x7FFFFFFFu) : ~ob);
}

// seg_starts (int4-vectorized) + mask dtype detect fused in block 0.
// flag: 0 = int32 mask, 1 = float mask, 2 = byte (bool) mask
__global__ void prep_kernel(const int* __restrict__ batch, int* __restrict__ start,
                            const unsigned int* __restrict__ mraw, int* __restrict__ flag,
                            int E) {
    if (blockIdx.x == 0 && threadIdx.x < 64) {
        int lane = threadIdx.x;
        bool allI = true, allF = true;
        for (int i = lane; i < 256; i += 64) {
            unsigned int w = mraw[i];
            if (w > 1u) allI = false;
            if (w != 0u && w != 0x3F800000u) allF = false;
        }
        allI = __all(allI);
        allF = __all(allF);
        if (lane == 0) *flag = allI ? 0 : (allF ? 1 : 2);
    }
    const int n4 = E >> 2;
    int i4 = blockIdx.x * blockDim.x + threadIdx.x;
    if (i4 >= n4) return;
    int4 b = ((const int4*)batch)[i4];
    int prev = __shfl_up(b.w, 1, 64);
    if ((threadIdx.x & 63) == 0) prev = (i4 == 0) ? -1 : batch[i4 * 4 - 1];
    const int e0 = i4 * 4;
    for (int g = prev + 1; g <= b.x; ++g) start[g] = e0;
    for (int g = b.x + 1; g <= b.y; ++g) start[g] = e0 + 1;
    for (int g = b.y + 1; g <= b.z; ++g) start[g] = e0 + 2;
    for (int g = b.z + 1; g <= b.w; ++g) start[g] = e0 + 3;
    if (i4 == n4 - 1) {
        int last = b.w, e = E & ~3;
        for (int t = 0; t < (E & 3); ++t) {
            int v = batch[e + t];
            for (int g = last + 1; g <= v; ++g) start[g] = e + t;
            last = v;
        }
        for (int g = last + 1; g <= G_NUM; ++g) start[g] = E;
    }
}

// 256-bucket suffix scan + k-th bucket select. Self-clears hist[0..255], resets *cnt2.
__device__ __forceinline__ void scan_select(
    unsigned int* hist, unsigned int* wtot, int kk,
    int* bsel_s, unsigned int* cgt_s, unsigned int* hsel_s, int* cnt2, int tid)
{
    unsigned int h = hist[tid];
    hist[tid] = 0u;
    unsigned int v = h;
    int lane = tid & 63, wv = tid >> 6;
    #pragma unroll
    for (int off = 1; off < 64; off <<= 1) {
        unsigned int o = __shfl_down(v, off, 64);
        if (lane + off < 64) v += o;
    }
    if (lane == 0) wtot[wv] = v;
    if (tid == 0) *cnt2 = 0;
    __syncthreads();
    unsigned int sfx = v;
    for (int w = wv + 1; w < 4; ++w) sfx += wtot[w];
    if ((unsigned)kk <= sfx && (unsigned)kk > sfx - h) {
        *bsel_s = tid; *cgt_s = sfx - h; *hsel_s = h;
    }
    __syncthreads();
}

// 2048-bucket version: thread owns buckets [8*tid, 8*tid+8). Self-clears, resets *cnt2.
__device__ __forceinline__ void scan_select2048(
    unsigned int* hist, unsigned int* wtot, int kk,
    int* bsel_s, unsigned int* cgt_s, unsigned int* hsel_s, int* cnt2, int tid)
{
    unsigned int h[8];
    unsigned int S = 0u;
    const int b0 = tid * 8;
    #pragma unroll
    for (int j = 0; j < 8; ++j) { h[j] = hist[b0 + j]; S += h[j]; hist[b0 + j] = 0u; }
    unsigned int v = S;
    int lane = tid & 63, wv = tid >> 6;
    #pragma unroll
    for (int off = 1; off < 64; off <<= 1) {
        unsigned int o = __shfl_down(v, off, 64);
        if (lane + off < 64) v += o;
    }
    if (lane == 0) wtot[wv] = v;
    if (tid == 0) *cnt2 = 0;
    __syncthreads();
    unsigned int sfx = v;
    for (int w = wv + 1; w < 4; ++w) sfx += wtot[w];
    unsigned int run = sfx - S;          // count of keys in buckets above this thread's
    #pragma unroll
    for (int j = 7; j >= 0; --j) {
        unsigned int inc = run + h[j];
        if ((unsigned)kk <= inc && (unsigned)kk > run) {
            *bsel_s = b0 + j; *cgt_s = run; *hsel_s = h[j];
        }
        run = inc;
    }
    __syncthreads();
}

__global__ __launch_bounds__(BLOCK) void topk_kernel(
    const float* __restrict__ scores, const void* __restrict__ maskp,
    const int* __restrict__ start, const int* __restrict__ kp,
    const int* __restrict__ flagp, float* __restrict__ out_mask,
    float* __restrict__ out_scores, int E)
{
    __shared__ unsigned int hist[HB];
    __shared__ unsigned int wtot[4];
    __shared__ ull cls[CLS];
    __shared__ int cnt, cnt2, bsel_s, licut_s;
    __shared__ unsigned int cgt_s, hsel_s, P_s;

    const int g  = blockIdx.x;
    const int s0 = start[g];
    const int s1 = start[g + 1];
    const int len = s1 - s0;
    if (len <= 0) return;

    const int k     = *kp;
    const int mflag = *flagp;
    const int tid   = threadIdx.x;

    auto getmask = [&](int i) -> bool {
        if (mflag == 2) return ((const unsigned char*)maskp)[i] != 0;
        if (mflag == 0) return ((const int*)maskp)[i] != 0;
        return ((const float*)maskp)[i] != 0.0f;
    };

    if (k <= 0) {
        for (int i = s0 + tid; i < s1; i += BLOCK) { out_mask[i] = 0.0f; out_scores[i] = 0.0f; }
        return;
    }

    #pragma unroll
    for (int j = 0; j < HB / BLOCK; ++j) hist[tid + j * BLOCK] = 0u;
    if (tid == 0) cnt = 0;

    if (len <= CAP) {
        const int a0 = s0 & ~3;            // 16B-aligned base
        unsigned int key[VPT];
        unsigned int candm = 0u;

        // ---- coalesced chunked loads: chunk q of thread t = [a0+4*(q*256+t), +4) ----
        #pragma unroll
        for (int q = 0; q < 3; ++q) {
            const int g0 = a0 + 4 * (q * BLOCK + tid);
            if (g0 >= s0 && g0 + 4 <= s1) {
                float4 f = *(const float4*)(scores + g0);
                key[4*q]   = order_bits(f.x);
                key[4*q+1] = order_bits(f.y);
                key[4*q+2] = order_bits(f.z);
                key[4*q+3] = order_bits(f.w);
                unsigned int cm4 = 0u;
                if (mflag == 2) {
                    unsigned int w = *(const unsigned int*)((const unsigned char*)maskp + g0);
                    #pragma unroll
                    for (int j = 0; j < 4; ++j)
                        if ((w >> (8*j)) & 0xFFu) cm4 |= 1u << j;
                } else if (mflag == 0) {
                    int4 w = *(const int4*)((const int*)maskp + g0);
                    if (w.x) cm4 |= 1u; if (w.y) cm4 |= 2u;
                    if (w.z) cm4 |= 4u; if (w.w) cm4 |= 8u;
                } else {
                    float4 w = *(const float4*)((const float*)maskp + g0);
                    if (w.x != 0.0f) cm4 |= 1u; if (w.y != 0.0f) cm4 |= 2u;
                    if (w.z != 0.0f) cm4 |= 4u; if (w.w != 0.0f) cm4 |= 8u;
                }
                candm |= cm4 << (4*q);
            } else if (g0 < s1) {          // edge chunk: per-element guarded
                #pragma unroll
                for (int j = 0; j < 4; ++j) {
                    int gi = g0 + j;
                    key[4*q+j] = 0u;
                    if (gi >= s0 && gi < s1) {
                        key[4*q+j] = order_bits(scores[gi]);
                        if (getmask(gi)) candm |= 1u << (4*q+j);
                    }
                }
            } else {
                #pragma unroll
                for (int j = 0; j < 4; ++j) key[4*q+j] = 0u;
            }
        }

        __syncthreads();                   // B1: hist/cnt clear visible
        #pragma unroll
        for (int v = 0; v < VPT; ++v)
            if ((candm >> v) & 1u) atomicAdd(&hist[key[v] >> 21], 1u);
        int lc = __popc(candm);
        #pragma unroll
        for (int off = 1; off < 64; off <<= 1) lc += __shfl_xor(lc, off, 64);
        if ((tid & 63) == 0) atomicAdd(&cnt, lc);
        __syncthreads();                   // B2: hist + m ready
        const int m = cnt;
        const bool keep_all = (m <= k);
        unsigned int P = 0u;
        int licut = 0;

        if (!keep_all) {
            int kk = k;
            scan_select2048(hist, wtot, kk, &bsel_s, &cgt_s, &hsel_s, &cnt2, tid);
            unsigned int prefix = ((unsigned int)bsel_s) << 21;
            kk -= (int)cgt_s;
            int csel = (int)hsel_s;
            int low  = 21;

            if (csel > CLS) {              // rare: continue with 8/8/5-bit rounds
                const int lows[3]   = {13, 5, 0};
                const int widths[3] = {8, 8, 5};
                for (int r = 0; r < 3; ++r) {
                    const int lw = lows[r], wd = widths[r];
                    const unsigned int dm = (1u << wd) - 1u;
                    #pragma unroll
                    for (int v = 0; v < VPT; ++v)
                        if (((candm >> v) & 1u) &&
                            ((key[v] >> (lw + wd)) == (prefix >> (lw + wd))))
                            atomicAdd(&hist[(key[v] >> lw) & dm], 1u);
                    __syncthreads();
                    scan_select(hist, wtot, kk, &bsel_s, &cgt_s, &hsel_s, &cnt2, tid);
                    prefix |= ((unsigned int)bsel_s) << lw;
                    kk  -= (int)cgt_s;
                    csel = (int)hsel_s;
                    low  = lw;
                    if (csel <= CLS) break;
                }
            }

            if (csel <= CLS) {
                // collect boundary class (matches prefix down to bit `low`)
                const int dl = a0 - s0;
                #pragma unroll
                for (int v = 0; v < VPT; ++v) {
                    if (((candm >> v) & 1u) && ((key[v] >> low) == (prefix >> low))) {
                        int q = v >> 2;
                        int li = dl + 4 * (q * BLOCK + tid) + (v & 3);
                        cls[atomicAdd(&cnt2, 1)] = ((ull)key[v] << 32) | (unsigned int)li;
                    }
                }
                __syncthreads();           // cls ready
                if (tid < csel) {
                    ull me = cls[tid];
                    unsigned int km = (unsigned int)(me >> 32), lm = (unsigned int)me;
                    int r = 0;
                    for (int j = 0; j < csel; ++j) {
                        ull o = cls[j];
                        unsigned int ko = (unsigned int)(o >> 32), lo = (unsigned int)o;
                        r += (ko > km || (ko == km && lo < lm)) ? 1 : 0;
                    }
                    if (r == kk - 1) { P_s = km; licut_s = (int)lm; }
                }
                __syncthreads();
                P = P_s; licut = licut_s;
            } else {
                // >CLS fully-identical keys: rank by li via count binary search
                P = prefix;
                const int dl = a0 - s0;
                int lo = 0, hi = len - 1;
                while (lo < hi) {
                    int mid = (lo + hi) >> 1;
                    if (tid == 0) cnt2 = 0;
                    __syncthreads();
                    int c = 0;
                    #pragma unroll
                    for (int v = 0; v < VPT; ++v) {
                        int q = v >> 2;
                        int li = dl + 4 * (q * BLOCK + tid) + (v & 3);
                        if (((candm >> v) & 1u) && key[v] == prefix && li <= mid) c++;
                    }
                    #pragma unroll
                    for (int off = 1; off < 64; off <<= 1) c += __shfl_xor(c, off, 64);
                    if ((tid & 63) == 0) atomicAdd(&cnt2, c);
                    __syncthreads();
                    int total = cnt2;
                    __syncthreads();
                    if (total >= kk) hi = mid; else lo = mid + 1;
                }
                licut = lo;
            }
        }

        // ---- coalesced chunked output straight from registers ----
        const int dl = a0 - s0;
        #pragma unroll
        for (int q = 0; q < 3; ++q) {
            const int g0 = a0 + 4 * (q * BLOCK + tid);
            if (g0 >= s0 && g0 + 4 <= s1) {
                float4 vm, vs;
                float* pm = (float*)&vm;
                float* ps = (float*)&vs;
                #pragma unroll
                for (int j = 0; j < 4; ++j) {
                    int v = 4*q + j;
                    int li = dl + 4 * (q * BLOCK + tid) + j;
                    bool kept = ((candm >> v) & 1u) &&
                        (keep_all || key[v] > P || (key[v] == P && li <= licut));
                    pm[j] = kept ? 1.0f : 0.0f;
                    ps[j] = kept ? inv_order_bits(key[v]) : 0.0f;
                }
                *(float4*)(out_mask   + g0) = vm;
                *(float4*)(out_scores + g0) = vs;
            } else if (g0 < s1) {
                #pragma unroll
                for (int j = 0; j < 4; ++j) {
                    int gi = g0 + j;
                    if (gi < s0 || gi >= s1) continue;
                    int v = 4*q + j;
                    int li = gi - s0;
                    bool kept = ((candm >> v) & 1u) &&
                        (keep_all || key[v] > P || (key[v] == P && li <= licut));
                    out_mask[gi]   = kept ? 1.0f : 0.0f;
                    out_scores[gi] = kept ? inv_order_bits(key[v]) : 0.0f;
                }
            }
        }
    } else {
        // ---- fallback: global-rescan 64-bit radix (len > CAP; ~never) ----
        __syncthreads();
        int lc = 0;
        for (int i = s0 + tid; i < s1; i += BLOCK)
            if (getmask(i)) lc++;
        atomicAdd(&cnt, lc);
        __syncthreads();
        const int m = cnt;
        const bool keep_all = (m <= k);
        ull pivot = 0ull;
        if (!keep_all) {
            ull prefix = 0ull;
            int kk = k;
            for (int shift = 56; shift >= 0; shift -= 8) {
                for (int i = s0 + tid; i < s1; i += BLOCK) {
                    if (!getmask(i)) continue;
                    ull key = ((ull)order_bits(scores[i]) << 32) |
                              (ull)(0xFFFFFFFFu - (unsigned)(i - s0));
                    if (shift == 56 || (key >> (shift + 8)) == (prefix >> (shift + 8)))
                        atomicAdd(&hist[(unsigned)((key >> shift) & 0xFFull)], 1u);
                }
                __syncthreads();
                scan_select(hist, wtot, kk, &bsel_s, &cgt_s, &hsel_s, &cnt2, tid);
                prefix |= ((ull)(unsigned)bsel_s) << shift;
                kk -= (int)cgt_s;
            }
            pivot = prefix;
        }
        for (int i = s0 + tid; i < s1; i += BLOCK) {
            bool c = getmask(i);
            float sc = 0.0f;
            bool kept = false;
            if (c) {
                sc = scores[i];
                ull key = ((ull)order_bits(sc) << 32) |
                          (ull)(0xFFFFFFFFu - (unsigned)(i - s0));
                kept = keep_all || (key >= pivot);
            }
            out_mask[i]   = kept ? 1.0f : 0.0f;
            out_scores[i] = kept ? sc : 0.0f;
        }
    }
}

extern "C" void kernel_launch(void* const* d_in, const int* in_sizes, int n_in,
                              void* d_out, int out_size, void* d_ws, size_t ws_size,
                              hipStream_t stream) {
    const float* scores = (const float*)d_in[0];
    const int*   batch  = (const int*)d_in[1];
    const void*  mask   = d_in[2];
    const int*   kp     = (const int*)d_in[4];
    const int    E      = in_sizes[0];

    float* out_mask   = (float*)d_out;
    float* out_scores = out_mask + E;

    int* flag  = (int*)d_ws;
    int* start = (int*)((char*)d_ws + 256);

    const int n4 = E >> 2;
    prep_kernel<<<(n4 + BLOCK - 1) / BLOCK, BLOCK, 0, stream>>>(
        batch, start, (const unsigned int*)mask, flag, E);
    topk_kernel<<<G_NUM, BLOCK, 0, stream>>>(scores, mask, start, kp, flag,
                                             out_mask, out_scores, E);
}